// Round 2
// 103.986 us; speedup vs baseline: 1.0017x; 1.0017x over previous
//
#include <hip/hip_runtime.h>
#include <stdint.h>

// Problem constants
#define NB   16      // batch
#define NC   128
#define NT   8
#define NBR  16
#define NS   8
#define NSY  64
#define NIN  16384   // = NC*NT*NBR = INPUT_SIZE

// ---------------------------------------------------------------------------
// Kernel A: pack x (B x NIN float 0/1) into per-position 16-bit batch masks.
// ---------------------------------------------------------------------------
__global__ __launch_bounds__(256) void k_pack(const float* __restrict__ x,
                                              uint16_t* __restrict__ xpack) {
    const int i = blockIdx.x * 256 + threadIdx.x;   // grid = 64*256 = NIN
    uint32_t m = 0;
#pragma unroll
    for (int b = 0; b < NB; ++b)
        m |= (x[b * NIN + i] != 0.0f) ? (1u << b) : 0u;
    xpack[i] = (uint16_t)m;
}

// ---------------------------------------------------------------------------
__device__ __forceinline__ void stage(const uint16_t* __restrict__ g,
                                      uint16_t* l, int tid) {
    const uint4* s = (const uint4*)g;
    uint4* d = (uint4*)l;
#pragma unroll
    for (int k = 0; k < 8; ++k) d[k * 256 + tid] = s[k * 256 + tid];
}

__device__ __forceinline__ uint32_t compress_even(uint32_t x) {
    // keep bits 0,2,4,...,30 -> pack into low 16 bits
    x &= 0x55555555u;
    x = (x | (x >> 1)) & 0x33333333u;
    x = (x | (x >> 2)) & 0x0F0F0F0Fu;
    x = (x | (x >> 4)) & 0x00FF00FFu;
    x = (x | (x >> 8)) & 0x0000FFFFu;
    return x;
}

// ---------------------------------------------------------------------------
// Batched transpose-popcount: one wave computes TWO branches' 16-batch masks.
// Phase G: gather ALL 8 segments x 2 branches (16 independent ds_read_u16 +
//   16 ds_write_b16 into 2 KB per-wave scratch, no fences -> deep ILP on the
//   random gathers).
// Phase R: lane = (branch<<5) | (batch<<1) | half. Each lane reads its half's
//   32 masks per segment (4 x ds_read_b128, 4 distinct addrs 2-way-bank-free
//   broadcast), popcounts its batch bit, ONE shfl_xor(1) to join halves,
//   per-segment threshold, then ONE ballot + even-bit compress for both
//   branch masks.
// ---------------------------------------------------------------------------
__device__ __forceinline__ void pair_masks(const uint16_t* __restrict__ lds16,
                                           uint16_t* __restrict__ s0,
                                           uint16_t* __restrict__ s1,
                                           const int* __restrict__ ip0,
                                           const int* __restrict__ ip1,
                                           int lane,
                                           uint32_t& om0, uint32_t& om1) {
    int iv0[NS], iv1[NS];
#pragma unroll
    for (int s = 0; s < NS; ++s) { iv0[s] = ip0[s * NSY]; iv1[s] = ip1[s * NSY]; }
    // Phase G: gather all segments for both branches into per-wave scratch.
#pragma unroll
    for (int s = 0; s < NS; ++s) {
        const uint32_t m0 = (uint32_t)lds16[iv0[s] & (NIN - 1)] & ~(uint32_t)(iv0[s] >> 31);
        const uint32_t m1 = (uint32_t)lds16[iv1[s] & (NIN - 1)] & ~(uint32_t)(iv1[s] >> 31);
        s0[s * 64 + lane] = (uint16_t)m0;
        s1[s * 64 + lane] = (uint16_t)m1;
    }
    __builtin_amdgcn_wave_barrier();   // writes before reads (same-wave DS in order)
    // Phase R: lane -> (branch, batch, half)
    const int half = lane & 1;
    const uint32_t sel = 0x00010001u << ((lane >> 1) & 15);
    const uint4* r = (const uint4*)((lane & 32) ? s1 : s0) + half * 4;
    int bs = 0;
#pragma unroll
    for (int s = 0; s < NS; ++s) {
        const uint4 a = r[s * 8 + 0], b = r[s * 8 + 1];
        const uint4 c = r[s * 8 + 2], d = r[s * 8 + 3];
        int cnt = __popc(a.x & sel) + __popc(a.y & sel) + __popc(a.z & sel) + __popc(a.w & sel)
                + __popc(b.x & sel) + __popc(b.y & sel) + __popc(b.z & sel) + __popc(b.w & sel)
                + __popc(c.x & sel) + __popc(c.y & sel) + __popc(c.z & sel) + __popc(c.w & sel)
                + __popc(d.x & sel) + __popc(d.y & sel) + __popc(d.z & sel) + __popc(d.w & sel);
        cnt += __shfl_xor(cnt, 1);              // join halves: full 64-synapse count
        bs += (cnt >= 16) ? 1 : 0;              // SEG_TH
    }
    const unsigned long long bal = __ballot(bs >= 4);   // BR_TH; bit l = br*32+batch*2+half
    om0 = compress_even((uint32_t)bal);
    om1 = compress_even((uint32_t)(bal >> 32));
}

// ---------------------------------------------------------------------------
// Layer 1: 1024 blocks x 256. 16 branches/block (2 per wave x 2 iters).
// LDS 32 KB stage + 8 KB scratch = 40 KB -> exactly 4 blocks/CU (160 KB).
// ---------------------------------------------------------------------------
__global__ __launch_bounds__(256, 4) void k_layer1(const uint16_t* __restrict__ xpack,
                                                   const int* __restrict__ idx1,
                                                   uint16_t* __restrict__ act1pack) {
    __shared__ __align__(16) uint16_t lds[NIN];          // 32 KB
    __shared__ __align__(16) uint16_t scr[4 * 2 * 512];  // 8 KB: 2 KB per wave
    const int tid = threadIdx.x, lane = tid & 63, wave = tid >> 6;
    stage(xpack, lds, tid);
    __syncthreads();
    uint16_t* s0 = scr + (wave * 2 + 0) * 512;
    uint16_t* s1 = scr + (wave * 2 + 1) * 512;
#pragma unroll
    for (int it = 0; it < 2; ++it) {
        const int b0 = blockIdx.x * 16 + wave * 4 + it * 2;
        const int b1 = b0 + 1;
        uint32_t om0, om1;
        pair_masks(lds, s0, s1,
                   idx1 + b0 * (NS * NSY) + lane,
                   idx1 + b1 * (NS * NSY) + lane,
                   lane, om0, om1);
        if (lane == 0) { act1pack[b0] = (uint16_t)om0; act1pack[b1] = (uint16_t)om1; }
    }
}

// ---------------------------------------------------------------------------
// Layer 2: t = 0 only, 2048 branches. 256 blocks x 256. 8 branches/block.
// ---------------------------------------------------------------------------
__global__ __launch_bounds__(256, 4) void k_layer2(const uint16_t* __restrict__ act1pack,
                                                   const int* __restrict__ idx2,
                                                   int* __restrict__ out) {
    __shared__ __align__(16) uint16_t lds[NIN];
    __shared__ __align__(16) uint16_t scr[4 * 2 * 512];
    const int tid = threadIdx.x, lane = tid & 63, wave = tid >> 6;
    stage(act1pack, lds, tid);
    __syncthreads();
    uint16_t* s0 = scr + (wave * 2 + 0) * 512;
    uint16_t* s1 = scr + (wave * 2 + 1) * 512;
    const int j0 = blockIdx.x * 8 + wave * 2;          // [0, 2048)
    const int j1 = j0 + 1;
    const int c0 = j0 >> 4, br0 = j0 & 15;
    const int c1 = j1 >> 4, br1 = j1 & 15;
    uint32_t om0, om1;
    pair_masks(lds, s0, s1,
               idx2 + (c0 * (NT * NBR) + br0) * (NS * NSY) + lane,
               idx2 + (c1 * (NT * NBR) + br1) * (NS * NSY) + lane,
               lane, om0, om1);
    if (lane < NB) {
        out[lane * (NC * NBR) + j0] = (int)((om0 >> lane) & 1u);
        out[lane * (NC * NBR) + j1] = (int)((om1 >> lane) & 1u);
    }
}

// ---------------------------------------------------------------------------
extern "C" void kernel_launch(void* const* d_in, const int* in_sizes, int n_in,
                              void* d_out, int out_size, void* d_ws, size_t ws_size,
                              hipStream_t stream) {
    const float* x    = (const float*)d_in[0];
    const int*   idx1 = (const int*)d_in[1];
    const int*   idx2 = (const int*)d_in[2];

    uint16_t* xpack    = (uint16_t*)d_ws;                       // 32 KB
    uint16_t* act1pack = (uint16_t*)((char*)d_ws + 32768);      // 32 KB
    int*      out      = (int*)d_out;

    k_pack  <<<NIN / 256, 256, 0, stream>>>(x, xpack);
    k_layer1<<<NIN / 16,  256, 0, stream>>>(xpack, idx1, act1pack);
    k_layer2<<<(NC * NBR) / 8, 256, 0, stream>>>(act1pack, idx2, out);
}